// Round 6
// baseline (191.197 us; speedup 1.0000x reference)
//
#include <hip/hip_runtime.h>
#include <stdint.h>

// LogSig depth-2 via MFMA, reg-staged panels (R14; R15/R16 = identical
// resubmits after GPUAcquisitionTimeouts — the reg-staging A/B is still
// unmeasured; no edits while blind).
// R13 post-mortem: removing our memset+atomics changed nothing (190.75 ->
// 191.14) -> the 512-MiB @ ~78us fillBufferAligned dispatches are HARNESS
// re-poison, ~155us of every measurement. Kernel slice ~= 35us (absent from
// top-5, 191 - 2x78 ~= 35). Kernel's own floor was the global_load_lds path
// (R10 fire-hose: 4.33 TB/s -> 31us). That is a PATH bound, not HW: dwordx4
// register loads hit 6.29 TB/s (m13), and x (134MB) is L3-resident across
// iterations. R14: reg-staging (T14) — global_load_dwordx4 -> VGPR ->
// ds_write_b128 into the IDENTICAL skewed LDS layout -> unchanged ds_read /
// frag / MFMA path. 3-panel register pipeline (g,g2,g3, full unroll = pure
// renaming), compiler emits counted vmcnt for reg deps. Halo = 2 direct
// dword loads per panel (row prefetched 2 iters earlier -> L2-warm),
// deleting the cross-buffer halo special cases.
// Prediction: kernel ~23-26us, dur_us 191 -> ~178-182, absmax 0.5 unchanged.
//
// Math (verified R4-R13, passed=true): M = sum_t x[t] (x) x[t+1], K=2047
// padded by row clamp (symmetric bogus term cancels); A = 0.5*(M - M^T -
// x0(x)L1 + L1(x)x0), L1 = x[2047]-x[0]; fp32 -> truncation hi/lo split,
// M ~= aH*bH + aH*bL + aL*bH, 12 MFMA/panel, absmax ~0.5.
//
// LDS layout (unchanged): panel = 32 rows = 4 chunks x (8 rows x 32 dw),
// chunk skew +8 dw -> e-reads land 2-way bank-aliased (free, m136).
// ds_write_b128 at lane*16B is linear -> conflict-free.

constexpr int kB   = 512;
constexpr int kL   = 2048;
constexpr int kD   = 32;
constexpr int kOut = 528;
constexpr int kPan = 32;            // rows per K=32 panel
constexpr int kTw  = 512;           // rows per wave (4 waves cover 2048)
constexpr int kNP  = kTw / kPan;    // 16 panels
constexpr int kCh  = 264;           // dwords per 8-row chunk (256 + 8 skew)
constexpr int kPB  = 4 * kCh;       // panel buffer (4 chunks)

typedef __attribute__((ext_vector_type(8))) short bfrag;
typedef __attribute__((ext_vector_type(4))) float f4acc;
typedef __attribute__((ext_vector_type(4))) uint32_t u32x4;
union FragU { uint32_t u[4]; bfrag f; };

__global__ __launch_bounds__(256, 2)
void logsig_mfma(const float* __restrict__ x, float* __restrict__ out) {
    __shared__ __align__(16) uint32_t sStage[4][2][kPB];   // 33.8 KB, wave-private
    __shared__ float sx0[kD], sL1[kD];

    const int b    = blockIdx.x;
    const int tid  = threadIdx.x;
    const int wave = tid >> 6;
    const int lane = tid & 63;
    const int m    = lane & 15;   // MFMA m/n index
    const int q    = lane >> 4;   // quad: k = q*8 + j

    const float* __restrict__ xb = x + (size_t)b * (kL * kD);
    const int t0w  = wave * kTw;
    const int grow = lane >> 3;        // row within 8-row chunk
    const int gcol = (lane & 7) * 4;   // dword col (16B per lane)

    // issue 4x global_load_dwordx4: one 32-row panel, 1KB line-dense per chunk.
    // rows never exceed kL-1 by construction (t0w+15*32+24+7 = 2047) -> no clamp.
    auto issue_g = [&](int p, u32x4 (&g)[4]) {
        const int rbase = t0w + p * kPan;
        #pragma unroll
        for (int c = 0; c < 4; ++c) {
            const uint32_t* gp = (const uint32_t*)xb
                               + (size_t)(rbase + c * 8 + grow) * kD + gcol;
            g[c] = *(const u32x4*)gp;
        }
    };
    // ds_write_b128 into the skewed chunk layout (same bytes global_load_lds
    // produced: chunk c dword o -> row o>>5, col o&31).
    auto write_g = [&](const u32x4 (&g)[4], int buf) {
        uint32_t* dst = &sStage[wave][buf][0];
        #pragma unroll
        for (int c = 0; c < 4; ++c)
            *(u32x4*)(dst + c * kCh + lane * 4) = g[c];
    };
    // halo: e[8] row = rbase + q*8 + 8, cols m / m+16. For q==3 that's panel
    // p+1 row 0 (prefetched 2 iters ago -> L2-warm); clamp covers sequence end
    // (clamped term is symmetric -> cancels in A).
    auto issue_h = [&](int p, uint32_t& h0, uint32_t& h1) {
        int hr = t0w + p * kPan + q * 8 + 8;
        hr = hr < kL - 1 ? hr : kL - 1;
        const uint32_t* gp = (const uint32_t*)xb + (size_t)hr * kD;
        h0 = gp[m];
        h1 = gp[m + 16];
    };

    f4acc acc[4];
    #pragma unroll
    for (int t = 0; t < 4; ++t)
        #pragma unroll
        for (int e = 0; e < 4; ++e) acc[t][e] = 0.0f;

    auto make_frags = [&](const uint32_t* e, FragU& AH, FragU& AL,
                          FragU& BH, FragU& BL) {
        uint32_t l[9];
        #pragma unroll
        for (int j = 0; j < 9; ++j) {
            const uint32_t fh = e[j] & 0xffff0000u;
            const float r = __builtin_bit_cast(float, e[j])
                          - __builtin_bit_cast(float, fh);
            l[j] = __builtin_bit_cast(uint32_t, r);
        }
        #pragma unroll
        for (int d = 0; d < 4; ++d) {
            AH.u[d] = __builtin_amdgcn_perm(e[2*d+1], e[2*d],   0x07060302u);
            AL.u[d] = __builtin_amdgcn_perm(l[2*d+1], l[2*d],   0x07060302u);
            BH.u[d] = __builtin_amdgcn_perm(e[2*d+2], e[2*d+1], 0x07060302u);
            BL.u[d] = __builtin_amdgcn_perm(l[2*d+2], l[2*d+1], 0x07060302u);
        }
    };

    // ---- prologue: fill buf0 with panel 0; start panels 1,2 in flight ----
    u32x4 g[4], g2[4], g3[4];
    issue_g(0, g);
    write_g(g, 0);           // compiler inserts vmcnt for g here
    issue_g(1, g);
    issue_g(2, g2);

    #pragma unroll
    for (int p = 0; p < kNP; ++p) {
        const int cu = p & 1, nb = cu ^ 1;

        uint32_t h0, h1;
        issue_h(p, h0, h1);                      // VMEM, mostly L1/L2 hits
        if (p + 3 < kNP) issue_g(p + 3, g3);     // keep ~2 panels in flight

        // e-reads of panel p (LDS pipe, no vmcnt dep) — issue before the
        // vmcnt-gated ds_writes below.
        const uint32_t* sb = &sStage[wave][cu][0];
        uint32_t e0[9], e1[9];
        #pragma unroll
        for (int j = 0; j < 8; ++j) {
            const int a = q * kCh + j * 32 + m;   // 2-way bank alias: free
            e0[j] = sb[a];
            e1[j] = sb[a + 16];
        }

        if (p + 1 < kNP) write_g(g, nb);          // panel p+1 -> other buffer
        if (p + 2 < kNP) {                        // register rotate (renamed
            #pragma unroll                        //  away by full unroll)
            for (int c = 0; c < 4; ++c) g[c] = g2[c];
        }
        if (p + 3 < kNP) {
            #pragma unroll
            for (int c = 0; c < 4; ++c) g2[c] = g3[c];
        }

        e0[8] = h0;
        e1[8] = h1;

        FragU A0H, A0L, B0H, B0L, A1H, A1L, B1H, B1L;
        make_frags(e0, A0H, A0L, B0H, B0L);
        make_frags(e1, A1H, A1L, B1H, B1L);

        acc[0] = __builtin_amdgcn_mfma_f32_16x16x32_bf16(A0H.f, B0H.f, acc[0], 0, 0, 0);
        acc[0] = __builtin_amdgcn_mfma_f32_16x16x32_bf16(A0H.f, B0L.f, acc[0], 0, 0, 0);
        acc[0] = __builtin_amdgcn_mfma_f32_16x16x32_bf16(A0L.f, B0H.f, acc[0], 0, 0, 0);
        acc[1] = __builtin_amdgcn_mfma_f32_16x16x32_bf16(A0H.f, B1H.f, acc[1], 0, 0, 0);
        acc[1] = __builtin_amdgcn_mfma_f32_16x16x32_bf16(A0H.f, B1L.f, acc[1], 0, 0, 0);
        acc[1] = __builtin_amdgcn_mfma_f32_16x16x32_bf16(A0L.f, B1H.f, acc[1], 0, 0, 0);
        acc[2] = __builtin_amdgcn_mfma_f32_16x16x32_bf16(A1H.f, B0H.f, acc[2], 0, 0, 0);
        acc[2] = __builtin_amdgcn_mfma_f32_16x16x32_bf16(A1H.f, B0L.f, acc[2], 0, 0, 0);
        acc[2] = __builtin_amdgcn_mfma_f32_16x16x32_bf16(A1L.f, B0H.f, acc[2], 0, 0, 0);
        acc[3] = __builtin_amdgcn_mfma_f32_16x16x32_bf16(A1H.f, B1H.f, acc[3], 0, 0, 0);
        acc[3] = __builtin_amdgcn_mfma_f32_16x16x32_bf16(A1H.f, B1L.f, acc[3], 0, 0, 0);
        acc[3] = __builtin_amdgcn_mfma_f32_16x16x32_bf16(A1L.f, B1H.f, acc[3], 0, 0, 0);
    }

    // ---- epilogue: overlay per-wave M on dead stage buffers, reduce, emit ----
    float* sWw = (float*)&sStage[wave][0][0];
    #pragma unroll
    for (int t = 0; t < 4; ++t) {
        const int tr = t >> 1, tc = t & 1;
        #pragma unroll
        for (int e = 0; e < 4; ++e) {
            const int row = 16 * tr + q * 4 + e;   // C/D layout (m89-verified)
            const int col = 16 * tc + m;
            sWw[row * kD + col] = acc[t][e];
        }
    }
    if (tid < kD) {
        const float x0v = xb[tid];
        const float xev = xb[(size_t)(kL - 1) * kD + tid];
        sx0[tid] = x0v;
        sL1[tid] = xev - x0v;
    }
    __syncthreads();

    float* sW0 = (float*)&sStage[0][0][0];
    for (int c = tid; c < kD * kD; c += 256)
        sW0[c] += ((float*)&sStage[1][0][0])[c]
                + ((float*)&sStage[2][0][0])[c]
                + ((float*)&sStage[3][0][0])[c];
    __syncthreads();

    // one block per sequence: plain stores, no memset, no atomics
    float* ob = out + (size_t)b * kOut;
    for (int o = tid; o < kOut; o += 256) {
        if (o < 32) {
            ob[o] = sL1[o];
        } else {
            int p = o - 32, i = 0;
            while (p >= 31 - i) { p -= 31 - i; ++i; }
            const int j = i + 1 + p;
            float v = 0.5f * (sW0[i * kD + j] - sW0[j * kD + i])
                    + 0.5f * (sx0[j] * sL1[i] - sx0[i] * sL1[j]);
            ob[o] = v;
        }
    }
}

extern "C" void kernel_launch(void* const* d_in, const int* in_sizes, int n_in,
                              void* d_out, int out_size, void* d_ws, size_t ws_size,
                              hipStream_t stream) {
    const float* x = (const float*)d_in[0];
    float* out = (float*)d_out;
    logsig_mfma<<<dim3(kB), dim3(256), 0, stream>>>(x, out);
}

// Round 8
// 188.549 us; speedup vs baseline: 1.0140x; 1.0140x over previous
//
#include <hip/hip_runtime.h>
#include <stdint.h>

// LogSig depth-2 via MFMA — R17: direct-to-register fragments, NO LDS staging.
// (R18 = identical resubmit after GPUAcquisitionTimeout; A/B still unmeasured.)
// History: R12-R16 measured four structurally different kernels (global_load_lds
// @(256,4)/(256,2), 1-block/seq, reg-staged 3-deep pipeline) -> total invariant
// 189.4-191.2 us. Decomposition: 2x77us harness re-poison fills (512 MiB each,
// immovable) + ~36us kernel slice, invariant across ALL staging rewrites.
// Kernel arithmetic: HBM cold floor 21.3us (fills evict L3) + VALU ~14.5us
// (hi/lo split) ~= 36 -> memory and VALU are SERIALIZED. Invariants across the
// four configs: LDS round-trip (lgkm-gated e-reads), occupancy 8 waves/CU,
// VALU cost. R17 removes the first two:
//  * fragments load DIRECTLY from global: e0[j]=x[r0+j][m] via one vaddr per
//    panel + immediate offsets j*128B; paired m/m+16 loads consume full 128B
//    lines -> exact 134MB traffic, zero LDS in the K-loop, zero barriers,
//    compiler emits counted vmcnt for the 1-panel-deep register prefetch.
//  * 512-thread blocks, 8 waves x 256 rows, grid 512 -> 16 waves/CU (4/SIMD),
//    launch_bounds(512,4) caps VGPR at 128 (live set ~110).
// Prediction: kernel ~22-26us -> total ~176-182; if invariant ~191 again, the
// slice is pinned by something outside all five structures -> roofline talk.
//
// Math (verified R4-R16, passed=true): M = sum_t x[t] (x) x[t+1], K=2047
// padded by row clamp (symmetric bogus term cancels); A = 0.5*(M - M^T -
// x0(x)L1 + L1(x)x0), L1 = x[2047]-x[0]; fp32 -> truncation hi/lo split,
// M ~= aH*bH + aH*bL + aL*bH, 12 MFMA/panel, absmax <= 0.5.

constexpr int kB   = 512;
constexpr int kL   = 2048;
constexpr int kD   = 32;
constexpr int kOut = 528;
constexpr int kPan = 32;            // rows per K=32 panel
constexpr int kTw  = 256;           // rows per wave (8 waves cover 2048)
constexpr int kNP  = kTw / kPan;    // 8 panels per wave

typedef __attribute__((ext_vector_type(8))) short bfrag;
typedef __attribute__((ext_vector_type(4))) float f4acc;
union FragU { uint32_t u[4]; bfrag f; };

__global__ __launch_bounds__(512, 4)
void logsig_mfma(const float* __restrict__ x, float* __restrict__ out) {
    __shared__ float sM[8][kD * kD];     // 32 KB: per-wave M tiles (epilogue only)
    __shared__ float sx0[kD], sL1[kD];

    const int b    = blockIdx.x;
    const int tid  = threadIdx.x;
    const int wave = tid >> 6;
    const int lane = tid & 63;
    const int m    = lane & 15;   // MFMA m/n index
    const int q    = lane >> 4;   // quad: k = q*8 + j

    const float* __restrict__ xb = x + (size_t)b * (kL * kD);
    const uint32_t* __restrict__ xu = (const uint32_t*)xb;
    const int t0w = wave * kTw;

    // Direct fragment load: e0[j] = x[r0+j][m], e1[j] = x[r0+j][m+16],
    // j=0..7 at immediate offsets j*128B from one per-panel vaddr; j=8 is the
    // halo row r0+8 (clamped at sequence end; clamped pair is symmetric ->
    // cancels in the antisymmetrization). Lanes (q,m) cover 4x64B segments
    // per instr; the m/m+16 pair consumes full 128B lines -> no over-fetch.
    auto load_panel = [&](int p, uint32_t (&e0)[9], uint32_t (&e1)[9]) {
        const int r0 = t0w + p * kPan + q * 8;
        const uint32_t* gp = xu + (size_t)r0 * kD + m;
        #pragma unroll
        for (int j = 0; j < 8; ++j) {
            e0[j] = gp[j * kD];
            e1[j] = gp[j * kD + 16];
        }
        int hr = r0 + 8;
        hr = hr < kL - 1 ? hr : kL - 1;      // only wave7/p7/q3 actually clamps
        const uint32_t* hp = xu + (size_t)hr * kD + m;
        e0[8] = hp[0];
        e1[8] = hp[16];
    };

    f4acc acc[4];
    #pragma unroll
    for (int t = 0; t < 4; ++t)
        #pragma unroll
        for (int e = 0; e < 4; ++e) acc[t][e] = 0.0f;

    auto make_frags = [&](const uint32_t* e, FragU& AH, FragU& AL,
                          FragU& BH, FragU& BL) {
        uint32_t l[9];
        #pragma unroll
        for (int j = 0; j < 9; ++j) {
            const uint32_t fh = e[j] & 0xffff0000u;
            const float r = __builtin_bit_cast(float, e[j])
                          - __builtin_bit_cast(float, fh);
            l[j] = __builtin_bit_cast(uint32_t, r);
        }
        #pragma unroll
        for (int d = 0; d < 4; ++d) {
            AH.u[d] = __builtin_amdgcn_perm(e[2*d+1], e[2*d],   0x07060302u);
            AL.u[d] = __builtin_amdgcn_perm(l[2*d+1], l[2*d],   0x07060302u);
            BH.u[d] = __builtin_amdgcn_perm(e[2*d+2], e[2*d+1], 0x07060302u);
            BL.u[d] = __builtin_amdgcn_perm(l[2*d+2], l[2*d+1], 0x07060302u);
        }
    };

    // double-buffered fragment registers, statically selected under full unroll
    uint32_t eA0[9], eA1[9], eB0[9], eB1[9];
    load_panel(0, eA0, eA1);

    #pragma unroll
    for (int p = 0; p < kNP; ++p) {
        const bool even = (p & 1) == 0;
        auto& c0 = even ? eA0 : eB0;
        auto& c1 = even ? eA1 : eB1;
        auto& n0 = even ? eB0 : eA0;
        auto& n1 = even ? eB1 : eA1;

        if (p + 1 < kNP) load_panel(p + 1, n0, n1);   // 18 loads in flight
                                                      // across this panel's math
        FragU A0H, A0L, B0H, B0L, A1H, A1L, B1H, B1L;
        make_frags(c0, A0H, A0L, B0H, B0L);
        make_frags(c1, A1H, A1L, B1H, B1L);

        acc[0] = __builtin_amdgcn_mfma_f32_16x16x32_bf16(A0H.f, B0H.f, acc[0], 0, 0, 0);
        acc[0] = __builtin_amdgcn_mfma_f32_16x16x32_bf16(A0H.f, B0L.f, acc[0], 0, 0, 0);
        acc[0] = __builtin_amdgcn_mfma_f32_16x16x32_bf16(A0L.f, B0H.f, acc[0], 0, 0, 0);
        acc[1] = __builtin_amdgcn_mfma_f32_16x16x32_bf16(A0H.f, B1H.f, acc[1], 0, 0, 0);
        acc[1] = __builtin_amdgcn_mfma_f32_16x16x32_bf16(A0H.f, B1L.f, acc[1], 0, 0, 0);
        acc[1] = __builtin_amdgcn_mfma_f32_16x16x32_bf16(A0L.f, B1H.f, acc[1], 0, 0, 0);
        acc[2] = __builtin_amdgcn_mfma_f32_16x16x32_bf16(A1H.f, B0H.f, acc[2], 0, 0, 0);
        acc[2] = __builtin_amdgcn_mfma_f32_16x16x32_bf16(A1H.f, B0L.f, acc[2], 0, 0, 0);
        acc[2] = __builtin_amdgcn_mfma_f32_16x16x32_bf16(A1L.f, B0H.f, acc[2], 0, 0, 0);
        acc[3] = __builtin_amdgcn_mfma_f32_16x16x32_bf16(A1H.f, B1H.f, acc[3], 0, 0, 0);
        acc[3] = __builtin_amdgcn_mfma_f32_16x16x32_bf16(A1H.f, B1L.f, acc[3], 0, 0, 0);
        acc[3] = __builtin_amdgcn_mfma_f32_16x16x32_bf16(A1L.f, B1H.f, acc[3], 0, 0, 0);
    }

    // ---- epilogue: per-wave M -> LDS, 8-wave reduce, emit ----
    float* sWw = sM[wave];
    #pragma unroll
    for (int t = 0; t < 4; ++t) {
        const int tr = t >> 1, tc = t & 1;
        #pragma unroll
        for (int e = 0; e < 4; ++e) {
            const int row = 16 * tr + q * 4 + e;   // C/D layout (m89-verified)
            const int col = 16 * tc + m;
            sWw[row * kD + col] = acc[t][e];
        }
    }
    if (tid < kD) {
        const float x0v = xb[tid];
        const float xev = xb[(size_t)(kL - 1) * kD + tid];
        sx0[tid] = x0v;
        sL1[tid] = xev - x0v;
    }
    __syncthreads();

    for (int c = tid; c < kD * kD; c += 512) {
        float s = sM[0][c];
        #pragma unroll
        for (int w = 1; w < 8; ++w) s += sM[w][c];
        sM[0][c] = s;
    }
    __syncthreads();

    float* ob = out + (size_t)b * kOut;
    for (int o = tid; o < kOut; o += 512) {
        if (o < 32) {
            ob[o] = sL1[o];
        } else {
            int p = o - 32, i = 0;
            while (p >= 31 - i) { p -= 31 - i; ++i; }
            const int j = i + 1 + p;
            float v = 0.5f * (sM[0][i * kD + j] - sM[0][j * kD + i])
                    + 0.5f * (sx0[j] * sL1[i] - sx0[i] * sL1[j]);
            ob[o] = v;
        }
    }
}

extern "C" void kernel_launch(void* const* d_in, const int* in_sizes, int n_in,
                              void* d_out, int out_size, void* d_ws, size_t ws_size,
                              hipStream_t stream) {
    const float* x = (const float*)d_in[0];
    float* out = (float*)d_out;
    logsig_mfma<<<dim3(kB), dim3(512), 0, stream>>>(x, out);
}